// Round 1
// baseline (557.411 us; speedup 1.0000x reference)
//
#include <hip/hip_runtime.h>
#include <cstdint>
#include <cstddef>

#define BATCH 16
#define CIN 512
#define COUT 512
#define STYLE_D 512
#define EPSC 1e-8f
#define CONV_SCALE_F 0.014731391274719739f   // 1/sqrt(512*9)
#define MOD_SCALE_F  0.04419417382415922f    // 1/sqrt(512)

typedef __attribute__((ext_vector_type(8))) short bhalf8;
typedef __attribute__((ext_vector_type(4))) float f32x4;

__device__ __forceinline__ unsigned short f2bf(float f){
  unsigned int u = __float_as_uint(f);
  u += 0x7fffu + ((u >> 16) & 1u);      // round-to-nearest-even
  return (unsigned short)(u >> 16);
}

__device__ __forceinline__ void load_lds16(const void* g, void* l){
  __builtin_amdgcn_global_load_lds(
      (const __attribute__((address_space(1))) uint32_t*)g,
      (__attribute__((address_space(3))) uint32_t*)l, 16, 0, 0);
}

// a[b,ci] = CONV_SCALE * (style[b,:] . mod_weight[ci,:] * MOD_SCALE + mod_bias[ci])
__global__ void k_style(const float* __restrict__ style, const float* __restrict__ mw,
                        const float* __restrict__ mb, float* __restrict__ a){
  int t = blockIdx.x * 256 + threadIdx.x;       // 8192
  int b = t >> 9, c = t & 511;
  const float4* s4 = (const float4*)(style + b * STYLE_D);
  const float4* w4 = (const float4*)(mw + (size_t)c * STYLE_D);
  float s = 0.f;
#pragma unroll 4
  for (int k = 0; k < STYLE_D / 4; ++k){
    float4 sv = s4[k], wv = w4[k];
    s += sv.x * wv.x + sv.y * wv.y + sv.z * wv.z + sv.w * wv.w;
  }
  s = s * MOD_SCALE_F + mb[c];
  a[t] = CONV_SCALE_F * s;
}

// r[co,ci] = sum_k conv^2 ; W2[tap][co][ci] = bf16(conv[co,ci,tap])
__global__ void k_wprep(const float* __restrict__ cw, float* __restrict__ r,
                        unsigned short* __restrict__ W2){
  int t = blockIdx.x * 256 + threadIdx.x;       // 262144 = co*512+ci
  int co = t >> 9, ci = t & 511;
  const float* w = cw + (size_t)t * 9;
  float acc = 0.f; float v[9];
#pragma unroll
  for (int j = 0; j < 9; ++j){ v[j] = w[j]; acc += v[j] * v[j]; }
  r[t] = acc;
#pragma unroll
  for (int tap = 0; tap < 9; ++tap)
    W2[((size_t)tap * COUT + co) * CIN + ci] = f2bf(v[tap]);
}

// d[b,co] = rsqrt( sum_ci a^2 * r + eps )
__global__ void k_demod(const float* __restrict__ a, const float* __restrict__ r,
                        float* __restrict__ d){
  int t = blockIdx.x * 256 + threadIdx.x;       // 8192
  int b = t >> 9, co = t & 511;
  const float4* a4 = (const float4*)(a + b * CIN);
  const float4* r4 = (const float4*)(r + (size_t)co * CIN);
  float s = 0.f;
#pragma unroll 4
  for (int k = 0; k < CIN / 4; ++k){
    float4 av = a4[k], rv = r4[k];
    s += av.x*av.x*rv.x + av.y*av.y*rv.y + av.z*av.z*rv.z + av.w*av.w*rv.w;
  }
  d[t] = rsqrtf(s + EPSC);
}

// x2[b][y][x][ci] = bf16( a[b,ci] * in[b,ci,y,x] )   (NCHW fp32 -> NHWC bf16, a folded)
__global__ void k_xprep(const float* __restrict__ in, const float* __restrict__ a,
                        unsigned short* __restrict__ x2){
  __shared__ float tile[32][65];
  int bx = blockIdx.x;                 // 16384 = b(16) * ct(16) * pt(64)
  int b  = bx >> 10;
  int ct = (bx >> 6) & 15;
  int pt = bx & 63;                    // one image row (64 px)
  int c0 = ct * 32, p0 = pt * 64;
  int t = threadIdx.x;
  int xx = t & 63, c4 = t >> 6;
  const float* src = in + ((size_t)b * CIN + c0) * 4096 + p0;
#pragma unroll
  for (int i = 0; i < 8; ++i){
    int cl = i * 4 + c4;
    tile[cl][xx] = src[(size_t)cl * 4096 + xx];
  }
  __syncthreads();
  int c = t & 31, p4 = t >> 5;
  float av = a[b * CIN + c0 + c];
  unsigned short* dst = x2 + ((size_t)b * 4096 + p0) * CIN + c0 + c;
#pragma unroll
  for (int i = 0; i < 8; ++i){
    int pl = i * 8 + p4;
    dst[(size_t)pl * CIN] = f2bf(av * tile[c][pl]);
  }
}

// Implicit-GEMM 3x3 conv, bf16 MFMA. Block: 64 co x 16x16 px, 16 cin-steps of 32.
// LDS slots (16B): input [c:4][iy:18][ix:18] = 1296 (+48 pad) ; weights [tap:9][q:4][co:64] = 2304.
#define NSLOT_IN 1344
#define NCHUNK 57                       // (1344+2304)/64
__global__ __launch_bounds__(256, 2) void k_conv(
    const unsigned short* __restrict__ x2, const unsigned short* __restrict__ W2,
    const float* __restrict__ d, const char* __restrict__ zp,
    float* __restrict__ out){
  __shared__ __align__(16) unsigned char smem[(NSLOT_IN + 2304) * 16];

  int bx = blockIdx.x;                 // 2048
  int b   = bx >> 7;
  int rem = bx & 127;
  int coT = rem >> 4;                  // 8 co-tiles of 64
  int pt  = rem & 15;                  // 16 pixel tiles of 16x16
  int y0 = (pt >> 2) * 16, x0 = (pt & 3) * 16;

  int tid = threadIdx.x, lane = tid & 63, w = tid >> 6;

  // -------- per-lane staging addresses (step-invariant; +64B/step = +32 cin) --------
  const int nch = (w == 0) ? 15 : 14;
  const char* ga[15];
#pragma unroll
  for (int i = 0; i < 15; ++i){
    if (i < nch){
      int ch = i * 4 + w;
      int slot = ch * 64 + lane;
      const char* p;
      if (slot < 1296){
        int c = slot / 324;
        int r2 = slot - c * 324;
        int iy = r2 / 18, ix = r2 - iy * 18;
        int gy = y0 + iy - 1, gx = x0 + ix - 1;
        if (gy >= 0 && gy < 64 && gx >= 0 && gx < 64)
          p = (const char*)x2 + (((size_t)b * 4096 + gy * 64 + gx) * CIN + c * 8) * 2;
        else
          p = zp;                       // zero page (branch-free OOB)
      } else if (slot < NSLOT_IN){
        p = zp;                         // LDS pad slots
      } else {
        int sw = slot - NSLOT_IN;
        int tap = sw >> 8, r2 = sw & 255, q = r2 >> 6, co = r2 & 63;
        p = (const char*)W2 + (((size_t)tap * COUT + coT * 64 + co) * CIN + q * 8) * 2;
      }
      ga[i] = p;
    }
  }

  const int q = lane >> 4, n = lane & 15;
  const unsigned int bBase = (unsigned)(q * 324 + n) * 16u;
  const unsigned int aBase = (unsigned)(NSLOT_IN + q * 64 + n) * 16u;

  f32x4 acc[4][4];
#pragma unroll
  for (int cf = 0; cf < 4; ++cf)
#pragma unroll
    for (int pf = 0; pf < 4; ++pf)
      acc[cf][pf] = (f32x4){0.f, 0.f, 0.f, 0.f};

  for (int s = 0; s < 16; ++s){
    // stage next 32-cin slab: 57 x global_load_lds_dwordx4 (all 64 lanes active)
#pragma unroll
    for (int i = 0; i < 15; ++i){
      if (i < nch){
        int ch = i * 4 + w;
        load_lds16(ga[i], smem + ch * 1024 + lane * 16);
        ga[i] += 64;
      }
    }
    __syncthreads();
#pragma unroll
    for (int tap = 0; tap < 9; ++tap){
      const int ki = tap / 3, kj = tap - ki * 3;
      bhalf8 av[4];
#pragma unroll
      for (int cf = 0; cf < 4; ++cf)
        av[cf] = *(const bhalf8*)(smem + aBase + (unsigned)(tap * 256 + cf * 16) * 16u);
#pragma unroll
      for (int pf = 0; pf < 4; ++pf){
        unsigned boff = bBase + (unsigned)(((w * 4 + pf + ki) * 18 + kj) * 16);
        bhalf8 bv = *(const bhalf8*)(smem + boff);
#pragma unroll
        for (int cf = 0; cf < 4; ++cf)
          acc[cf][pf] = __builtin_amdgcn_mfma_f32_16x16x32_bf16(av[cf], bv, acc[cf][pf], 0, 0, 0);
      }
    }
    __syncthreads();
  }

  // epilogue: D layout col=lane&15 (x), row=(lane>>4)*4+r (co); scale by d[b,co]
  const float* dp = d + b * COUT;
  int rowq = (lane >> 4) * 4;
#pragma unroll
  for (int cf = 0; cf < 4; ++cf){
#pragma unroll
    for (int r = 0; r < 4; ++r){
      int co = coT * 64 + cf * 16 + rowq + r;
      float dv = dp[co];
      float* op = out + (((size_t)b * COUT + co) * 64 + y0 + w * 4) * 64 + x0 + n;
#pragma unroll
      for (int pf = 0; pf < 4; ++pf)
        op[(size_t)pf * 64] = dv * acc[cf][pf][r];
    }
  }
}

// ---------------- fallback (small ws): correct fp32 direct conv ----------------
__global__ void k_demod_direct(const float* __restrict__ a, const float* __restrict__ cw,
                               float* __restrict__ d){
  int t = blockIdx.x * 256 + threadIdx.x;   // 8192
  int b = t & 15, co = t >> 4;
  const float* ar = a + b * CIN;
  const float* wr = cw + (size_t)co * CIN * 9;
  float s = 0.f;
  for (int ci = 0; ci < CIN; ++ci){
    float av = ar[ci], rr = 0.f;
#pragma unroll
    for (int j = 0; j < 9; ++j){ float v = wr[ci * 9 + j]; rr += v * v; }
    s += av * av * rr;
  }
  d[b * COUT + co] = rsqrtf(s + EPSC);
}

__global__ void k_conv_naive(const float* __restrict__ in, const float* __restrict__ cw,
                             const float* __restrict__ a, const float* __restrict__ d,
                             float* __restrict__ out){
  size_t t = (size_t)blockIdx.x * 256 + threadIdx.x;
  int x = t & 63, y = (t >> 6) & 63;
  int co = (t >> 12) & 511, b = (int)(t >> 21);
  const float* ar = a + b * CIN;
  const float* wr = cw + (size_t)co * CIN * 9;
  const float* ib = in + (size_t)b * CIN * 4096;
  float acc = 0.f;
  for (int ci = 0; ci < CIN; ++ci){
    float av = ar[ci];
    const float* ip = ib + (size_t)ci * 4096;
    const float* wp = wr + ci * 9;
#pragma unroll
    for (int dy = 0; dy < 3; ++dy){
      int gy = y + dy - 1;
      if (gy < 0 || gy > 63) continue;
#pragma unroll
      for (int dx = 0; dx < 3; ++dx){
        int gx = x + dx - 1;
        if (gx < 0 || gx > 63) continue;
        acc += wp[dy * 3 + dx] * av * ip[gy * 64 + gx];
      }
    }
  }
  out[t] = d[b * COUT + co] * acc;
}

extern "C" void kernel_launch(void* const* d_in, const int* in_sizes, int n_in,
                              void* d_out, int out_size, void* d_ws, size_t ws_size,
                              hipStream_t stream){
  (void)in_sizes; (void)n_in; (void)out_size;
  const float* in    = (const float*)d_in[0];
  const float* style = (const float*)d_in[1];
  const float* cw    = (const float*)d_in[2];
  const float* mw    = (const float*)d_in[3];
  const float* mb    = (const float*)d_in[4];
  float* out = (float*)d_out;

  char* ws = (char*)d_ws;
  const size_t ZP_OFF = 0;                              // 4KB zero page
  const size_t A_OFF  = 4096;                           // 32KB
  const size_t D_OFF  = A_OFF + 32768;                  // 32KB
  const size_t R_OFF  = D_OFF + 32768;                  // 1MB
  const size_t W2_OFF = R_OFF + 1048576;                // 4.5MB bf16 weights
  const size_t X2_OFF = W2_OFF + (size_t)9 * COUT * CIN * 2;
  const size_t WS_NEED = X2_OFF + (size_t)BATCH * 4096 * CIN * 2;  // +67MB bf16 NHWC input

  float* a    = (float*)(ws + A_OFF);
  float* dmod = (float*)(ws + D_OFF);

  if (ws_size >= WS_NEED){
    float* r = (float*)(ws + R_OFF);
    unsigned short* W2 = (unsigned short*)(ws + W2_OFF);
    unsigned short* x2 = (unsigned short*)(ws + X2_OFF);
    hipMemsetAsync(ws + ZP_OFF, 0, 4096, stream);
    k_style<<<32, 256, 0, stream>>>(style, mw, mb, a);
    k_wprep<<<1024, 256, 0, stream>>>(cw, r, W2);
    k_demod<<<32, 256, 0, stream>>>(a, r, dmod);
    k_xprep<<<16384, 256, 0, stream>>>(in, a, x2);
    k_conv<<<2048, 256, 0, stream>>>(x2, W2, dmod, ws + ZP_OFF, out);
  } else {
    k_style<<<32, 256, 0, stream>>>(style, mw, mb, a);
    k_demod_direct<<<32, 256, 0, stream>>>(a, cw, dmod);
    k_conv_naive<<<131072, 256, 0, stream>>>(in, cw, a, dmod, out);
  }
}

// Round 2
// 527.675 us; speedup vs baseline: 1.0564x; 1.0564x over previous
//
#include <hip/hip_runtime.h>
#include <cstdint>
#include <cstddef>

#define BATCH 16
#define CIN 512
#define COUT 512
#define STYLE_D 512
#define EPSC 1e-8f
#define CONV_SCALE_F 0.014731391274719739f   // 1/sqrt(512*9)
#define MOD_SCALE_F  0.04419417382415922f    // 1/sqrt(512)

typedef __attribute__((ext_vector_type(8))) short bhalf8;
typedef __attribute__((ext_vector_type(16))) float f32x16;

__device__ __forceinline__ unsigned short f2bf(float f){
  unsigned int u = __float_as_uint(f);
  u += 0x7fffu + ((u >> 16) & 1u);      // round-to-nearest-even
  return (unsigned short)(u >> 16);
}

__device__ __forceinline__ void load_lds16(const void* g, void* l){
  __builtin_amdgcn_global_load_lds(
      (const __attribute__((address_space(1))) uint32_t*)g,
      (__attribute__((address_space(3))) uint32_t*)l, 16, 0, 0);
}

// a[b,ci] = CONV_SCALE * (style[b,:] . mod_weight[ci,:] * MOD_SCALE + mod_bias[ci])
__global__ void k_style(const float* __restrict__ style, const float* __restrict__ mw,
                        const float* __restrict__ mb, float* __restrict__ a){
  int t = blockIdx.x * 256 + threadIdx.x;       // 8192
  int b = t >> 9, c = t & 511;
  const float4* s4 = (const float4*)(style + b * STYLE_D);
  const float4* w4 = (const float4*)(mw + (size_t)c * STYLE_D);
  float s = 0.f;
#pragma unroll 4
  for (int k = 0; k < STYLE_D / 4; ++k){
    float4 sv = s4[k], wv = w4[k];
    s += sv.x * wv.x + sv.y * wv.y + sv.z * wv.z + sv.w * wv.w;
  }
  s = s * MOD_SCALE_F + mb[c];
  a[t] = CONV_SCALE_F * s;
}

// r[co,ci] = sum_k conv^2 ; W2[tap][co][ci] = bf16(conv[co,ci,tap])
__global__ void k_wprep(const float* __restrict__ cw, float* __restrict__ r,
                        unsigned short* __restrict__ W2){
  int t = blockIdx.x * 256 + threadIdx.x;       // 262144 = co*512+ci
  int co = t >> 9, ci = t & 511;
  const float* w = cw + (size_t)t * 9;
  float acc = 0.f; float v[9];
#pragma unroll
  for (int j = 0; j < 9; ++j){ v[j] = w[j]; acc += v[j] * v[j]; }
  r[t] = acc;
#pragma unroll
  for (int tap = 0; tap < 9; ++tap)
    W2[((size_t)tap * COUT + co) * CIN + ci] = f2bf(v[tap]);
}

// d[b,co] = rsqrt( sum_ci a^2 * r + eps )
__global__ void k_demod(const float* __restrict__ a, const float* __restrict__ r,
                        float* __restrict__ d){
  int t = blockIdx.x * 256 + threadIdx.x;       // 8192
  int b = t >> 9, co = t & 511;
  const float4* a4 = (const float4*)(a + b * CIN);
  const float4* r4 = (const float4*)(r + (size_t)co * CIN);
  float s = 0.f;
#pragma unroll 4
  for (int k = 0; k < CIN / 4; ++k){
    float4 av = a4[k], rv = r4[k];
    s += av.x*av.x*rv.x + av.y*av.y*rv.y + av.z*av.z*rv.z + av.w*av.w*rv.w;
  }
  d[t] = rsqrtf(s + EPSC);
}

// x2[b][y][x][ci] = bf16( a[b,ci] * in[b,ci,y,x] )  (NCHW fp32 -> NHWC bf16, a folded)
// Block: 64 cin x 64 px (one image row). Writes: lane=cin-pair -> full 128B lines.
__global__ __launch_bounds__(256) void k_xprep(const float* __restrict__ in,
                                               const float* __restrict__ a,
                                               unsigned short* __restrict__ x2){
  __shared__ float tile[64][67];
  int bx = blockIdx.x;                 // 8192 = b(16) * cgrp(8) * y(64)
  int b = bx >> 9, cgrp = (bx >> 6) & 7, y = bx & 63;
  int c0 = cgrp * 64;
  int tid = threadIdx.x;
  int xx = tid & 63, c4 = tid >> 6;
  const float* src = in + ((size_t)(b * CIN + c0)) * 4096 + y * 64;
#pragma unroll
  for (int i = 0; i < 16; ++i){
    int cl = i * 4 + c4;
    tile[cl][xx] = src[(size_t)cl * 4096 + xx];
  }
  __syncthreads();
  int cg = tid & 31;
  float a0 = a[b * CIN + c0 + cg * 2];
  float a1 = a[b * CIN + c0 + cg * 2 + 1];
  unsigned int* dst = (unsigned int*)(x2 + ((size_t)(b * 4096 + y * 64)) * CIN + c0);
#pragma unroll
  for (int i = 0; i < 8; ++i){
    int px = i * 8 + (tid >> 5);
    float v0 = tile[cg * 2][px], v1 = tile[cg * 2 + 1][px];
    unsigned int pack = (unsigned int)f2bf(a0 * v0) | ((unsigned int)f2bf(a1 * v1) << 16);
    dst[(size_t)px * (CIN / 2) + cg] = pack;
  }
}

// Implicit-GEMM 3x3 conv, 32x32x16 bf16 MFMA.
// Block: 64 co x (32x16) px tile, 4 waves; wave = 64 co x (32x4) px; 32 cin-steps of 16.
// LDS slots (16B): input [pix:612][kh:2] = 1224 ; weights [tap:9][cf:2][kh:2][co:32] = 1152;
// scrap 2376..2559 (dummy staging). slot == chunk id (identity -> valid lds dst).
#define LDS_W_BASE 19584
#define NCHUNK_TOT 2376
__global__ __launch_bounds__(256, 2) void k_conv(
    const unsigned short* __restrict__ x2, const unsigned short* __restrict__ W2,
    const float* __restrict__ dmod, const char* __restrict__ zp,
    float* __restrict__ out){
  __shared__ __align__(16) unsigned char smem[2560 * 16];

  int bx = blockIdx.x;                 // 1024 = b(16) * coT(8) * pt(8)
  int b = bx >> 6, coT = (bx >> 3) & 7, pt = bx & 7;
  int y0 = (pt >> 1) * 16, x0 = (pt & 1) * 32;
  int tid = threadIdx.x, lane = tid & 63, w = tid >> 6;

  // ---- staging pointers: exactly 10 chunks/thread (no divergence), +32B/step ----
  const char* ga[10];
#pragma unroll
  for (int i = 0; i < 10; ++i){
    int chunk = i * 256 + tid;
    const char* p;
    if (chunk < 1224){
      int pix = chunk >> 1, kh = chunk & 1;
      int iy = pix / 34, ix = pix - iy * 34;
      int gy = y0 + iy - 1, gx = x0 + ix - 1;
      if (gy >= 0 && gy < 64 && gx >= 0 && gx < 64)
        p = (const char*)x2 + (((size_t)(b * 4096 + gy * 64 + gx)) * CIN + kh * 8) * 2;
      else p = zp;
    } else if (chunk < NCHUNK_TOT){
      int sw = chunk - 1224;
      int tap = sw >> 7, cf = (sw >> 6) & 1, kh = (sw >> 5) & 1, co = sw & 31;
      p = (const char*)W2 + (((size_t)(tap * COUT + coT * 64 + cf * 32 + co)) * CIN + kh * 8) * 2;
    } else {
      p = zp;                          // dummy -> scrap LDS slots
    }
    ga[i] = p;
  }

  f32x16 acc[2][4];
#pragma unroll
  for (int cf = 0; cf < 2; ++cf)
#pragma unroll
    for (int nf = 0; nf < 4; ++nf)
#pragma unroll
      for (int e = 0; e < 16; ++e) acc[cf][nf][e] = 0.f;

  const unsigned bvLane = (unsigned)((lane & 31) * 32 + (lane >> 5) * 16);
  const unsigned char* wbase = smem + LDS_W_BASE + lane * 16;
  const unsigned wrow = (unsigned)(w * 4);

  for (int s = 0; s < 32; ++s){
#pragma unroll
    for (int i = 0; i < 10; ++i){
      load_lds16(ga[i], smem + (i * 256 + tid) * 16);
      ga[i] += 32;                     // next 16-cin slab
    }
    __syncthreads();
#pragma unroll
    for (int tap = 0; tap < 9; ++tap){
      const int ki = tap / 3, kj = tap - ki * 3;
      bhalf8 a0 = *(const bhalf8*)(wbase + tap * 2048);
      bhalf8 a1 = *(const bhalf8*)(wbase + tap * 2048 + 1024);
#pragma unroll
      for (int nf = 0; nf < 4; ++nf){
        bhalf8 bv = *(const bhalf8*)(smem + ((wrow + nf + ki) * 34 + kj) * 32 + bvLane);
        acc[0][nf] = __builtin_amdgcn_mfma_f32_32x32x16_bf16(a0, bv, acc[0][nf], 0, 0, 0);
        acc[1][nf] = __builtin_amdgcn_mfma_f32_32x32x16_bf16(a1, bv, acc[1][nf], 0, 0, 0);
      }
    }
    __syncthreads();
  }

  // epilogue: D col = lane&31 (px x), row = (reg&3)+8*(reg>>2)+4*(lane>>5) (co); scale by d
  int n = lane & 31, kh = lane >> 5;
  const float* dp = dmod + b * COUT + coT * 64;
#pragma unroll
  for (int cf = 0; cf < 2; ++cf){
#pragma unroll
    for (int nf = 0; nf < 4; ++nf){
      int gy = y0 + w * 4 + nf;
      float* orow = out + ((size_t)(b * COUT + coT * 64 + cf * 32)) * 4096 + gy * 64 + x0 + n;
#pragma unroll
      for (int reg = 0; reg < 16; ++reg){
        int row = (reg & 3) + 8 * (reg >> 2) + 4 * kh;
        orow[(size_t)row * 4096] = dp[cf * 32 + row] * acc[cf][nf][reg];
      }
    }
  }
}

// ---------------- fallback (small ws): correct fp32 direct conv ----------------
__global__ void k_demod_direct(const float* __restrict__ a, const float* __restrict__ cw,
                               float* __restrict__ d){
  int t = blockIdx.x * 256 + threadIdx.x;   // 8192
  int b = t & 15, co = t >> 4;
  const float* ar = a + b * CIN;
  const float* wr = cw + (size_t)co * CIN * 9;
  float s = 0.f;
  for (int ci = 0; ci < CIN; ++ci){
    float av = ar[ci], rr = 0.f;
#pragma unroll
    for (int j = 0; j < 9; ++j){ float v = wr[ci * 9 + j]; rr += v * v; }
    s += av * av * rr;
  }
  d[b * COUT + co] = rsqrtf(s + EPSC);
}

__global__ void k_conv_naive(const float* __restrict__ in, const float* __restrict__ cw,
                             const float* __restrict__ a, const float* __restrict__ d,
                             float* __restrict__ out){
  size_t t = (size_t)blockIdx.x * 256 + threadIdx.x;
  int x = t & 63, y = (t >> 6) & 63;
  int co = (t >> 12) & 511, b = (int)(t >> 21);
  const float* ar = a + b * CIN;
  const float* wr = cw + (size_t)co * CIN * 9;
  const float* ib = in + (size_t)b * CIN * 4096;
  float acc = 0.f;
  for (int ci = 0; ci < CIN; ++ci){
    float av = ar[ci];
    const float* ip = ib + (size_t)ci * 4096;
    const float* wp = wr + ci * 9;
#pragma unroll
    for (int dy = 0; dy < 3; ++dy){
      int gy = y + dy - 1;
      if (gy < 0 || gy > 63) continue;
#pragma unroll
      for (int dx = 0; dx < 3; ++dx){
        int gx = x + dx - 1;
        if (gx < 0 || gx > 63) continue;
        acc += wp[dy * 3 + dx] * av * ip[gy * 64 + gx];
      }
    }
  }
  out[t] = d[b * COUT + co] * acc;
}

extern "C" void kernel_launch(void* const* d_in, const int* in_sizes, int n_in,
                              void* d_out, int out_size, void* d_ws, size_t ws_size,
                              hipStream_t stream){
  (void)in_sizes; (void)n_in; (void)out_size;
  const float* in    = (const float*)d_in[0];
  const float* style = (const float*)d_in[1];
  const float* cw    = (const float*)d_in[2];
  const float* mw    = (const float*)d_in[3];
  const float* mb    = (const float*)d_in[4];
  float* out = (float*)d_out;

  char* ws = (char*)d_ws;
  const size_t ZP_OFF = 0;                              // 4KB zero page
  const size_t A_OFF  = 4096;
  const size_t D_OFF  = A_OFF + 32768;
  const size_t R_OFF  = D_OFF + 32768;
  const size_t W2_OFF = R_OFF + 1048576;
  const size_t X2_OFF = W2_OFF + (size_t)9 * COUT * CIN * 2;
  const size_t WS_NEED = X2_OFF + (size_t)BATCH * 4096 * CIN * 2;

  float* a    = (float*)(ws + A_OFF);
  float* dmod = (float*)(ws + D_OFF);

  if (ws_size >= WS_NEED){
    float* r = (float*)(ws + R_OFF);
    unsigned short* W2 = (unsigned short*)(ws + W2_OFF);
    unsigned short* x2 = (unsigned short*)(ws + X2_OFF);
    hipMemsetAsync(ws + ZP_OFF, 0, 4096, stream);
    k_style<<<32, 256, 0, stream>>>(style, mw, mb, a);
    k_wprep<<<1024, 256, 0, stream>>>(cw, r, W2);
    k_demod<<<32, 256, 0, stream>>>(a, r, dmod);
    k_xprep<<<8192, 256, 0, stream>>>(in, a, x2);
    k_conv<<<1024, 256, 0, stream>>>(x2, W2, dmod, ws + ZP_OFF, out);
  } else {
    k_style<<<32, 256, 0, stream>>>(style, mw, mb, a);
    k_demod_direct<<<32, 256, 0, stream>>>(a, cw, dmod);
    k_conv_naive<<<131072, 256, 0, stream>>>(in, cw, a, dmod, out);
  }
}

// Round 3
// 512.757 us; speedup vs baseline: 1.0871x; 1.0291x over previous
//
#include <hip/hip_runtime.h>
#include <cstdint>
#include <cstddef>

#define BATCH 16
#define CIN 512
#define COUT 512
#define STYLE_D 512
#define EPSC 1e-8f
#define CONV_SCALE_F 0.014731391274719739f   // 1/sqrt(512*9)
#define MOD_SCALE_F  0.04419417382415922f    // 1/sqrt(512)

typedef __attribute__((ext_vector_type(8))) short bhalf8;
typedef __attribute__((ext_vector_type(16))) float f32x16;

__device__ __forceinline__ unsigned short f2bf(float f){
  unsigned int u = __float_as_uint(f);
  u += 0x7fffu + ((u >> 16) & 1u);      // round-to-nearest-even
  return (unsigned short)(u >> 16);
}

__device__ __forceinline__ void load_lds16(const void* g, void* l){
  __builtin_amdgcn_global_load_lds(
      (const __attribute__((address_space(1))) uint32_t*)g,
      (__attribute__((address_space(3))) uint32_t*)l, 16, 0, 0);
}

// ---- fused prep 1: style modulation (blocks 0..31) + weight prep (32..1055) ----
__global__ __launch_bounds__(256) void k_prep1(
    const float* __restrict__ style, const float* __restrict__ mw,
    const float* __restrict__ mb, const float* __restrict__ cw,
    float* __restrict__ a, float* __restrict__ r, unsigned short* __restrict__ W2){
  int bx = blockIdx.x;
  if (bx < 32){
    // a[b,ci] = CONV_SCALE * (style . mw*MOD_SCALE + mb)
    int t = bx * 256 + threadIdx.x;       // 8192
    int b = t >> 9, c = t & 511;
    const float4* s4 = (const float4*)(style + b * STYLE_D);
    const float4* w4 = (const float4*)(mw + (size_t)c * STYLE_D);
    float s = 0.f;
#pragma unroll 4
    for (int k = 0; k < STYLE_D / 4; ++k){
      float4 sv = s4[k], wv = w4[k];
      s += sv.x * wv.x + sv.y * wv.y + sv.z * wv.z + sv.w * wv.w;
    }
    s = s * MOD_SCALE_F + mb[c];
    a[t] = CONV_SCALE_F * s;
  } else {
    // r[co,ci] = sum_k conv^2 ; W2[tap][co][ci] = bf16(conv[co,ci,tap])
    int t = (bx - 32) * 256 + threadIdx.x; // 262144 = co*512+ci
    int co = t >> 9, ci = t & 511;
    const float* w = cw + (size_t)t * 9;
    float acc = 0.f; float v[9];
#pragma unroll
    for (int j = 0; j < 9; ++j){ v[j] = w[j]; acc += v[j] * v[j]; }
    r[t] = acc;
#pragma unroll
    for (int tap = 0; tap < 9; ++tap)
      W2[((size_t)tap * COUT + co) * CIN + ci] = f2bf(v[tap]);
  }
}

// ---- fused prep 2: xprep (blocks 0..8191) + demod (8192..8223) ----
__global__ __launch_bounds__(256) void k_prep2(
    const float* __restrict__ in, const float* __restrict__ a,
    const float* __restrict__ r, unsigned short* __restrict__ x2,
    float* __restrict__ d){
  __shared__ float tile[64][67];
  int bx = blockIdx.x;
  if (bx < 8192){
    // x2[b][y][x][ci] = bf16( a[b,ci] * in[b,ci,y,x] )
    int b = bx >> 9, cgrp = (bx >> 6) & 7, y = bx & 63;
    int c0 = cgrp * 64;
    int tid = threadIdx.x;
    int xx = tid & 63, c4 = tid >> 6;
    const float* src = in + ((size_t)(b * CIN + c0)) * 4096 + y * 64;
#pragma unroll
    for (int i = 0; i < 16; ++i){
      int cl = i * 4 + c4;
      tile[cl][xx] = src[(size_t)cl * 4096 + xx];
    }
    __syncthreads();
    int cg = tid & 31;
    float a0 = a[b * CIN + c0 + cg * 2];
    float a1 = a[b * CIN + c0 + cg * 2 + 1];
    unsigned int* dst = (unsigned int*)(x2 + ((size_t)(b * 4096 + y * 64)) * CIN + c0);
#pragma unroll
    for (int i = 0; i < 8; ++i){
      int px = i * 8 + (tid >> 5);
      float v0 = tile[cg * 2][px], v1 = tile[cg * 2 + 1][px];
      unsigned int pack = (unsigned int)f2bf(a0 * v0) | ((unsigned int)f2bf(a1 * v1) << 16);
      dst[(size_t)px * (CIN / 2) + cg] = pack;
    }
  } else {
    // d[b,co] = rsqrt( sum_ci a^2 * r + eps )
    int t = (bx - 8192) * 256 + threadIdx.x;  // 8192
    int b = t >> 9, co = t & 511;
    const float4* a4 = (const float4*)(a + b * CIN);
    const float4* r4 = (const float4*)(r + (size_t)co * CIN);
    float s = 0.f;
#pragma unroll 4
    for (int k = 0; k < CIN / 4; ++k){
      float4 av = a4[k], rv = r4[k];
      s += av.x*av.x*rv.x + av.y*av.y*rv.y + av.z*av.z*rv.z + av.w*av.w*rv.w;
    }
    d[t] = rsqrtf(s + EPSC);
  }
}

// Implicit-GEMM 3x3 conv, 32x32x16 bf16 MFMA, double-buffered LDS, 1 barrier/step.
// Block: 64 co x (32x16) px, 4 waves; wave = 64 co x (32x4) px; 32 cin-steps of 16.
// Buffer (2496 slots x 16B = 39936B): input slots 0..1223 ([pix:612][kh:2]),
// weights 1224..2375 ([tap:9][cf:2][kh:2][co:32]), pad 2376..2431, scrap 2432..2495.
// Two buffers = 79872 B LDS; 2 blocks/CU = 159744 <= 163840.
#define BUFSZ 39936
#define W_LDS_OFF 19584                  // 1224*16
__global__ __launch_bounds__(256, 2) void k_conv(
    const char* __restrict__ ws, const float* __restrict__ dmod,
    float* __restrict__ out,
    unsigned int x2_off, unsigned int w2_off){
  __shared__ __align__(16) unsigned char smem[2 * BUFSZ];

  int bx = blockIdx.x;                 // 1024 = b(16) * coT(8) * pt(8)
  int b = bx >> 6, coT = (bx >> 3) & 7, pt = bx & 7;
  int y0 = (pt >> 1) * 16, x0 = (pt & 1) * 32;
  int tid = threadIdx.x, lane = tid & 63, w = tid >> 6;

  // ---- staging maps: 10 chunks/thread; src = ws + off (u32), dst = buf + dst_off ----
  unsigned int off[10], dst_off[10];
#pragma unroll
  for (int i = 0; i < 10; ++i){
    int chunk = i * 256 + tid;
    int slot = (chunk < 2432) ? chunk : (2432 + (chunk & 63));
    dst_off[i] = (unsigned)slot * 16u;
    unsigned int o;
    if (chunk < 1224){
      int pix = chunk >> 1, kh = chunk & 1;
      int iy = pix / 34, ix = pix - iy * 34;
      int gy = y0 + iy - 1, gx = x0 + ix - 1;
      if (gy >= 0 && gy < 64 && gx >= 0 && gx < 64)
        o = x2_off + (unsigned)(((b * 4096 + gy * 64 + gx) * CIN + kh * 8) * 2);
      else o = 0;                       // zero page at ws[0]
    } else if (chunk < 2376){
      int sw = chunk - 1224;
      int tap = sw >> 7, cf = (sw >> 6) & 1, kh = (sw >> 5) & 1, co = sw & 31;
      o = w2_off + (unsigned)(((tap * COUT + coT * 64 + cf * 32 + co) * CIN + kh * 8) * 2);
    } else {
      o = 0;                            // pad/dummy -> zero page
    }
    off[i] = o;
  }

  f32x16 acc[2][4];
#pragma unroll
  for (int cf = 0; cf < 2; ++cf)
#pragma unroll
    for (int nf = 0; nf < 4; ++nf)
#pragma unroll
      for (int e = 0; e < 16; ++e) acc[cf][nf][e] = 0.f;

  const unsigned bvLane = (unsigned)((lane & 31) * 32 + (lane >> 5) * 16);
  const unsigned aLane  = (unsigned)(W_LDS_OFF + lane * 16);
  const unsigned wrow   = (unsigned)(w * 4);

  // prologue: stage step 0 into buffer 0
#pragma unroll
  for (int i = 0; i < 10; ++i){
    load_lds16(ws + off[i], smem + dst_off[i]);
    off[i] += 32;
  }
  __syncthreads();

  unsigned pbase = 0;
  for (int s = 0; s < 32; ++s){
    unsigned pnext = pbase ^ BUFSZ;
    if (s < 31){
#pragma unroll
      for (int i = 0; i < 10; ++i){
        load_lds16(ws + off[i], smem + pnext + dst_off[i]);
        off[i] += 32;
      }
    }
    const unsigned char* buf = smem + pbase;
#pragma unroll
    for (int kj = 0; kj < 3; ++kj){
      bhalf8 bv[6];
#pragma unroll
      for (int rr = 0; rr < 6; ++rr)
        bv[rr] = *(const bhalf8*)(buf + ((wrow + rr) * 34 + kj) * 32 + bvLane);
#pragma unroll
      for (int ki = 0; ki < 3; ++ki){
        int tap = ki * 3 + kj;
        bhalf8 a0 = *(const bhalf8*)(buf + aLane + tap * 2048);
        bhalf8 a1 = *(const bhalf8*)(buf + aLane + tap * 2048 + 1024);
#pragma unroll
        for (int nf = 0; nf < 4; ++nf){
          acc[0][nf] = __builtin_amdgcn_mfma_f32_32x32x16_bf16(a0, bv[nf + ki], acc[0][nf], 0, 0, 0);
          acc[1][nf] = __builtin_amdgcn_mfma_f32_32x32x16_bf16(a1, bv[nf + ki], acc[1][nf], 0, 0, 0);
        }
      }
    }
    __syncthreads();
    pbase = pnext;
  }

  // epilogue: D col = lane&31 (px x), row = (reg&3)+8*(reg>>2)+4*(lane>>5) (co)
  int n = lane & 31, kh = lane >> 5;
  const float* dp = dmod + b * COUT + coT * 64;
#pragma unroll
  for (int cf = 0; cf < 2; ++cf){
#pragma unroll
    for (int nf = 0; nf < 4; ++nf){
      int gy = y0 + w * 4 + nf;
      float* orow = out + ((size_t)(b * COUT + coT * 64 + cf * 32)) * 4096 + gy * 64 + x0 + n;
#pragma unroll
      for (int reg = 0; reg < 16; ++reg){
        int row = (reg & 3) + 8 * (reg >> 2) + 4 * kh;
        orow[(size_t)row * 4096] = dp[cf * 32 + row] * acc[cf][nf][reg];
      }
    }
  }
}

// ---------------- fallback (small ws): correct fp32 direct conv ----------------
__global__ void k_style_f(const float* __restrict__ style, const float* __restrict__ mw,
                          const float* __restrict__ mb, float* __restrict__ a){
  int t = blockIdx.x * 256 + threadIdx.x;
  int b = t >> 9, c = t & 511;
  const float* s = style + b * STYLE_D;
  const float* wv = mw + (size_t)c * STYLE_D;
  float acc = 0.f;
  for (int k = 0; k < STYLE_D; ++k) acc += s[k] * wv[k];
  a[t] = CONV_SCALE_F * (acc * MOD_SCALE_F + mb[c]);
}

__global__ void k_demod_direct(const float* __restrict__ a, const float* __restrict__ cw,
                               float* __restrict__ d){
  int t = blockIdx.x * 256 + threadIdx.x;   // 8192
  int b = t & 15, co = t >> 4;
  const float* ar = a + b * CIN;
  const float* wr = cw + (size_t)co * CIN * 9;
  float s = 0.f;
  for (int ci = 0; ci < CIN; ++ci){
    float av = ar[ci], rr = 0.f;
#pragma unroll
    for (int j = 0; j < 9; ++j){ float v = wr[ci * 9 + j]; rr += v * v; }
    s += av * av * rr;
  }
  d[b * COUT + co] = rsqrtf(s + EPSC);
}

__global__ void k_conv_naive(const float* __restrict__ in, const float* __restrict__ cw,
                             const float* __restrict__ a, const float* __restrict__ d,
                             float* __restrict__ out){
  size_t t = (size_t)blockIdx.x * 256 + threadIdx.x;
  int x = t & 63, y = (t >> 6) & 63;
  int co = (t >> 12) & 511, b = (int)(t >> 21);
  const float* ar = a + b * CIN;
  const float* wr = cw + (size_t)co * CIN * 9;
  const float* ib = in + (size_t)b * CIN * 4096;
  float acc = 0.f;
  for (int ci = 0; ci < CIN; ++ci){
    float av = ar[ci];
    const float* ip = ib + (size_t)ci * 4096;
    const float* wp = wr + ci * 9;
#pragma unroll
    for (int dy = 0; dy < 3; ++dy){
      int gy = y + dy - 1;
      if (gy < 0 || gy > 63) continue;
#pragma unroll
      for (int dx = 0; dx < 3; ++dx){
        int gx = x + dx - 1;
        if (gx < 0 || gx > 63) continue;
        acc += wp[dy * 3 + dx] * av * ip[gy * 64 + gx];
      }
    }
  }
  out[t] = d[b * COUT + co] * acc;
}

extern "C" void kernel_launch(void* const* d_in, const int* in_sizes, int n_in,
                              void* d_out, int out_size, void* d_ws, size_t ws_size,
                              hipStream_t stream){
  (void)in_sizes; (void)n_in; (void)out_size;
  const float* in    = (const float*)d_in[0];
  const float* style = (const float*)d_in[1];
  const float* cw    = (const float*)d_in[2];
  const float* mw    = (const float*)d_in[3];
  const float* mb    = (const float*)d_in[4];
  float* out = (float*)d_out;

  char* ws = (char*)d_ws;
  const size_t ZP_OFF = 0;                              // 4KB zero page
  const size_t A_OFF  = 4096;
  const size_t D_OFF  = A_OFF + 32768;
  const size_t R_OFF  = D_OFF + 32768;
  const size_t W2_OFF = R_OFF + 1048576;
  const size_t X2_OFF = W2_OFF + (size_t)9 * COUT * CIN * 2;
  const size_t WS_NEED = X2_OFF + (size_t)BATCH * 4096 * CIN * 2;

  float* a    = (float*)(ws + A_OFF);
  float* dmod = (float*)(ws + D_OFF);

  if (ws_size >= WS_NEED){
    float* r = (float*)(ws + R_OFF);
    unsigned short* W2 = (unsigned short*)(ws + W2_OFF);
    unsigned short* x2 = (unsigned short*)(ws + X2_OFF);
    hipMemsetAsync(ws + ZP_OFF, 0, 4096, stream);
    k_prep1<<<1056, 256, 0, stream>>>(style, mw, mb, cw, a, r, W2);
    k_prep2<<<8224, 256, 0, stream>>>(in, a, r, x2, dmod);
    k_conv<<<1024, 256, 0, stream>>>(ws, dmod, out,
                                     (unsigned int)X2_OFF, (unsigned int)W2_OFF);
  } else {
    k_style_f<<<32, 256, 0, stream>>>(style, mw, mb, a);
    k_demod_direct<<<32, 256, 0, stream>>>(a, cw, dmod);
    k_conv_naive<<<131072, 256, 0, stream>>>(in, cw, a, dmod, out);
  }
}